// Round 1
// baseline (2878.638 us; speedup 1.0000x reference)
//
#include <hip/hip_runtime.h>

// ---------------------------------------------------------------------------
// SparsePoolingLayer: u0 = conv5x5_valid(x, W_ff); iterate
//   u <- 0.5*u + 0.5*(u0 - W_rec @ a); a = relu(u - thr)
// until ||u_new - u||/||u_new|| < 1e-3 (checked on device), max 41 iterations.
// Shapes: x(32,64,64,64) f32, W_ff(256,64,5,5), W_rec(256,256), thr(256).
// Output a_final (32,256,60,60) f32.
//
// Design:
//  - bf16 MFMA 16x16x32 for conv (implicit GEMM, K reordered (ky,kx,ci)) and
//    the per-iteration channel GEMM. fp32 accumulate everywhere.
//  - u state is fp32 and lives in d_out (NCHW) -> final kernel is in-place relu.
//  - u0 stored bf16 [oc][n]; a stored bf16 [n][oc] (n = b*3600 + y*60 + x).
//  - Convergence: each iteration atomicAdds (diff^2, norm^2) into its slot;
//    iteration k+1 reads slot k; once converged a flag makes remaining
//    launches no-ops. Fixed 41 launches -> graph-capture safe.
// ---------------------------------------------------------------------------

typedef __attribute__((ext_vector_type(8))) short short8;
typedef __attribute__((ext_vector_type(4))) float f32x4;

#define NTOT 115200   // 32*60*60
#define CHW  262144   // 64*64*64
#define HW2  4096     // 64*64

__device__ __forceinline__ unsigned short f2bf(float f) {
  unsigned int u = __float_as_uint(f);
  unsigned int r = u + 0x7FFFu + ((u >> 16) & 1u);
  return (unsigned short)(r >> 16);
}
__device__ __forceinline__ float bf2f(unsigned short h) {
  return __uint_as_float(((unsigned int)h) << 16);
}

// ---------------------------------------------------------------------------
// Weight cast/reorder: W_ff[o][ci][ky][kx] -> wff[o][(ky*5+kx)*64 + ci] bf16
//                      W_rec[o][i]         -> wrec[o*256+i] bf16
__global__ void cast_weights(const float* __restrict__ wff_f,
                             const float* __restrict__ wrec_f,
                             unsigned short* __restrict__ wff,
                             unsigned short* __restrict__ wrec) {
  int tid = blockIdx.x * 256 + threadIdx.x;
  if (tid < 409600) {
    int o = tid / 1600, k = tid % 1600;
    int kk = k >> 6, ci = k & 63;            // k = kk*64 + ci
    wff[tid] = f2bf(wff_f[o * 1600 + ci * 25 + kk]);
  } else if (tid < 409600 + 65536) {
    int i = tid - 409600;
    wrec[i] = f2bf(wrec_f[i]);
  }
}

// ---------------------------------------------------------------------------
// Conv as implicit GEMM. Block tile 128(oc) x 128(n), BK=32. Grid (900, 2).
// Writes u0_cn bf16 [oc][n] and a0 into a_nc bf16 [n][oc].
__global__ __launch_bounds__(256) void conv_kernel(
    const float* __restrict__ x, const float* __restrict__ thr,
    const unsigned short* __restrict__ wff,
    unsigned short* __restrict__ u0_cn, unsigned short* __restrict__ a_nc) {
  __shared__ short As[128 * 40];   // [m][k] pad 32->40
  __shared__ short Bs[128 * 40];   // [n][k]
  const int t = threadIdx.x;
  const int n0 = blockIdx.x * 128;
  const int m0 = blockIdx.y * 128;
  const int lane = t & 63, w = t >> 6;
  const int q = lane >> 4, r = lane & 15;
  const int wm = w >> 1, wn = w & 1;

  // B-staging per-thread spatial decode (same n for both octet passes)
  const int bn = t & 127;
  const int ng = n0 + bn;
  const int bb = ng / 3600;
  const int rem = ng - bb * 3600;
  const int yy = rem / 60;
  const int xx = rem - yy * 60;
  const int bybase = bb * CHW + yy * 64 + xx;
  const int boct0 = t >> 7;        // octets boct0 and boct0+2

  f32x4 acc[4][4];
#pragma unroll
  for (int i = 0; i < 4; i++)
#pragma unroll
    for (int j = 0; j < 4; j++) acc[i][j] = (f32x4){0.f, 0.f, 0.f, 0.f};

  for (int c = 0; c < 50; ++c) {
    const int k0 = c * 32;
    const int kk = c >> 1;                 // ky*5+kx, uniform per chunk
    const int ky = kk / 5, kx = kk - ky * 5;
    const int cibase = (c & 1) * 32;
    const int gbase = bybase + ky * 64 + kx;

    __syncthreads();
    // stage A: 128 rows x 32 k = 512 x 16B tasks, 2 passes
#pragma unroll
    for (int p = 0; p < 2; ++p) {
      int s = p * 256 + t;
      int m = s >> 2, qt = s & 3;
      *(int4*)(&As[m * 40 + qt * 8]) =
          *(const int4*)(wff + (m0 + m) * 1600 + k0 + qt * 8);
    }
    // stage B: gather x (fp32), convert, write 8-bf16 groups
#pragma unroll
    for (int p = 0; p < 2; ++p) {
      int oct = boct0 + p * 2;
      int ci = cibase + oct * 8;
      alignas(16) unsigned short tmp[8];
#pragma unroll
      for (int jj = 0; jj < 8; ++jj)
        tmp[jj] = f2bf(x[gbase + (ci + jj) * HW2]);
      *(int4*)(&Bs[bn * 40 + oct * 8]) = *(const int4*)tmp;
    }
    __syncthreads();

    short8 af[4], bfr[4];
#pragma unroll
    for (int i = 0; i < 4; i++)
      af[i] = *(const short8*)(&As[(wm * 64 + i * 16 + r) * 40 + q * 8]);
#pragma unroll
    for (int j = 0; j < 4; j++)
      bfr[j] = *(const short8*)(&Bs[(wn * 64 + j * 16 + r) * 40 + q * 8]);
#pragma unroll
    for (int i = 0; i < 4; i++)
#pragma unroll
      for (int j = 0; j < 4; j++)
        acc[i][j] = __builtin_amdgcn_mfma_f32_16x16x32_bf16(af[i], bfr[j],
                                                            acc[i][j], 0, 0, 0);
  }

  // epilogue: u0 bf16 + a0 = relu(u0 - thr) bf16
#pragma unroll
  for (int i = 0; i < 4; i++) {
    const int ocb = m0 + wm * 64 + i * 16 + q * 4;
    float th[4] = {thr[ocb], thr[ocb + 1], thr[ocb + 2], thr[ocb + 3]};
#pragma unroll
    for (int j = 0; j < 4; j++) {
      const int n = n0 + wn * 64 + j * 16 + r;
      alignas(8) unsigned short ap[4];
#pragma unroll
      for (int d = 0; d < 4; ++d) {
        float v = acc[i][j][d];
        u0_cn[(ocb + d) * NTOT + n] = f2bf(v);
        float a = v - th[d];
        ap[d] = f2bf(a > 0.f ? a : 0.f);
      }
      *(uint2*)(&a_nc[n * 256 + ocb]) = *(const uint2*)ap;
    }
  }
}

// ---------------------------------------------------------------------------
// One fixed-point iteration: rec = W_rec @ a, u update, a update, norms.
// Block tile: full M=256 x 64(n). Grid 1800. 4 waves, wave w owns oc [w*64,w*64+64).
template <int FIRST>
__global__ __launch_bounds__(256) void iter_kernel(
    const unsigned short* __restrict__ wrec,
    const unsigned short* __restrict__ u0_cn, const float* __restrict__ thr,
    float* __restrict__ u, unsigned short* __restrict__ a_nc,
    float* __restrict__ norms, int* __restrict__ flag, int it) {
  __shared__ short As[256 * 40];
  __shared__ short Bs[64 * 40];
  __shared__ float red[8];

  const int t = threadIdx.x;
  if (!FIRST) {
    if (*(volatile int*)flag) return;                      // converged earlier
    float d2p = norms[2 * (it - 1)], n2p = norms[2 * (it - 1) + 1];
    if (d2p < 1e-6f * n2p) {                               // ref: fro ratio < 1e-3
      if (t == 0) *flag = 1;
      return;
    }
  }

  const int n0 = blockIdx.x * 64;
  const int lane = t & 63, w = t >> 6;
  const int q = lane >> 4, r = lane & 15;
  const int bn = t >> 2, bq = t & 3;       // B staging: row, 8-elem quarter

  f32x4 acc[4][4];
#pragma unroll
  for (int i = 0; i < 4; i++)
#pragma unroll
    for (int j = 0; j < 4; j++) acc[i][j] = (f32x4){0.f, 0.f, 0.f, 0.f};

  for (int c = 0; c < 8; ++c) {
    const int k0 = c * 32;
    __syncthreads();
#pragma unroll
    for (int p = 0; p < 4; ++p) {          // A: 256 rows x 32 k = 1024 tasks
      int s = p * 256 + t;
      int m = s >> 2, qt = s & 3;
      *(int4*)(&As[m * 40 + qt * 8]) =
          *(const int4*)(wrec + m * 256 + k0 + qt * 8);
    }
    *(int4*)(&Bs[bn * 40 + bq * 8]) =
        *(const int4*)(a_nc + (n0 + bn) * 256 + k0 + bq * 8);
    __syncthreads();

    short8 af[4], bfr[4];
#pragma unroll
    for (int i = 0; i < 4; i++)
      af[i] = *(const short8*)(&As[(w * 64 + i * 16 + r) * 40 + q * 8]);
#pragma unroll
    for (int j = 0; j < 4; j++)
      bfr[j] = *(const short8*)(&Bs[(j * 16 + r) * 40 + q * 8]);
#pragma unroll
    for (int i = 0; i < 4; i++)
#pragma unroll
      for (int j = 0; j < 4; j++)
        acc[i][j] = __builtin_amdgcn_mfma_f32_16x16x32_bf16(af[i], bfr[j],
                                                            acc[i][j], 0, 0, 0);
  }

  // fused update epilogue
  float d2 = 0.f, n2 = 0.f;
#pragma unroll
  for (int j = 0; j < 4; j++) {
    const int n = n0 + j * 16 + r;
    const int b = n / 3600;
    const int s = n - b * 3600;
    const int ubase = b * 921600 + s;      // NCHW: b*256*3600 + oc*3600 + s
#pragma unroll
    for (int i = 0; i < 4; i++) {
      const int ocb = w * 64 + i * 16 + q * 4;
      alignas(8) unsigned short ap[4];
#pragma unroll
      for (int d = 0; d < 4; ++d) {
        const int oc = ocb + d;
        float u0v = bf2f(u0_cn[oc * NTOT + n]);
        float uo = FIRST ? 0.f : u[ubase + oc * 3600];
        float un = 0.5f * uo + 0.5f * (u0v - acc[i][j][d]);
        u[ubase + oc * 3600] = un;
        float df = un - uo;
        d2 += df * df;
        n2 += un * un;
        float a = un - thr[oc];
        ap[d] = f2bf(a > 0.f ? a : 0.f);
      }
      *(uint2*)(&a_nc[n * 256 + ocb]) = *(const uint2*)ap;
    }
  }

  // block reduction -> atomicAdd into this iteration's norm slots
#pragma unroll
  for (int off = 32; off; off >>= 1) {
    d2 += __shfl_down(d2, off, 64);
    n2 += __shfl_down(n2, off, 64);
  }
  if (lane == 0) { red[w] = d2; red[4 + w] = n2; }
  __syncthreads();
  if (t == 0) {
    atomicAdd(&norms[2 * it], red[0] + red[1] + red[2] + red[3]);
    atomicAdd(&norms[2 * it + 1], red[4] + red[5] + red[6] + red[7]);
  }
}

// ---------------------------------------------------------------------------
// Final: out = relu(u - thr) in place (u already NCHW fp32 in d_out).
__global__ __launch_bounds__(256) void final_relu(float* __restrict__ out,
                                                  const float* __restrict__ thr) {
  int idx = blockIdx.x * 256 + threadIdx.x;
  int base = idx * 4;
  int c = (base / 3600) & 255;
  float th = thr[c];
  float4 v = *(float4*)(out + base);
  v.x = fmaxf(v.x - th, 0.f);
  v.y = fmaxf(v.y - th, 0.f);
  v.z = fmaxf(v.z - th, 0.f);
  v.w = fmaxf(v.w - th, 0.f);
  *(float4*)(out + base) = v;
}

// ---------------------------------------------------------------------------
extern "C" void kernel_launch(void* const* d_in, const int* in_sizes, int n_in,
                              void* d_out, int out_size, void* d_ws,
                              size_t ws_size, hipStream_t stream) {
  const float* x      = (const float*)d_in[0];
  const float* wff_f  = (const float*)d_in[1];
  const float* wrec_f = (const float*)d_in[2];
  const float* thr    = (const float*)d_in[3];
  float* u = (float*)d_out;  // u state lives in d_out (NCHW fp32)

  char* ws = (char*)d_ws;
  int* flag = (int*)ws;                                   // [0,4)
  float* norms = (float*)(ws + 64);                       // [64, 416)
  unsigned short* wff  = (unsigned short*)(ws + 1024);    // 819200 B
  unsigned short* wrec = (unsigned short*)(ws + 851968);  // 131072 B
  unsigned short* u0   = (unsigned short*)(ws + 1048576); // 58982400 B
  unsigned short* a    = (unsigned short*)(ws + 60030976);// 58982400 B
  // total ws needed: ~119 MB

  hipMemsetAsync(d_ws, 0, 1024, stream);  // flag + norm slots
  cast_weights<<<1856, 256, 0, stream>>>(wff_f, wrec_f, wff, wrec);
  conv_kernel<<<dim3(900, 2), 256, 0, stream>>>(x, thr, wff, u0, a);
  iter_kernel<1><<<1800, 256, 0, stream>>>(wrec, u0, thr, u, a, norms, flag, 1);
  for (int it = 2; it <= 41; ++it)   // max_iter = 20*2 = 40 -> up to 41 bodies
    iter_kernel<0><<<1800, 256, 0, stream>>>(wrec, u0, thr, u, a, norms, flag, it);
  final_relu<<<28800, 256, 0, stream>>>(u, thr);
}

// Round 2
// 1824.253 us; speedup vs baseline: 1.5780x; 1.5780x over previous
//
#include <hip/hip_runtime.h>

// ---------------------------------------------------------------------------
// SparsePoolingLayer: u0 = conv5x5_valid(x, W_ff); iterate
//   u <- 0.5*u + 0.5*(u0 - W_rec @ a); a = relu(u - thr)
// until ||u_new - u||/||u_new|| < 1e-3 (device-checked), max 41 iterations.
//
// R1 change: GEMMs compute D[n][oc] (A = data with M=n, B = weights with
// N=oc) so each lane's 4 C-regs are consecutive n -> u (NCHW) accessed as
// float4, u0 ([oc][n] bf16) as uint2. Kills the scalar-epilogue latency wall
// seen in R0 (hbm 16%, occupancy 10%, 265us/iter).
// ---------------------------------------------------------------------------

typedef __attribute__((ext_vector_type(8))) short short8;
typedef __attribute__((ext_vector_type(4))) float f32x4;

#define NTOT 115200   // 32*60*60
#define CHW  262144   // 64*64*64
#define HW2  4096     // 64*64

__device__ __forceinline__ unsigned short f2bf(float f) {
  unsigned int u = __float_as_uint(f);
  unsigned int r = u + 0x7FFFu + ((u >> 16) & 1u);
  return (unsigned short)(r >> 16);
}
__device__ __forceinline__ float bf2f(unsigned short h) {
  return __uint_as_float(((unsigned int)h) << 16);
}

// ---------------------------------------------------------------------------
// Weight cast/reorder: W_ff[o][ci][ky][kx] -> wff[o][(ky*5+kx)*64 + ci] bf16
//                      W_rec[o][i]         -> wrec[o*256+i] bf16
__global__ void cast_weights(const float* __restrict__ wff_f,
                             const float* __restrict__ wrec_f,
                             unsigned short* __restrict__ wff,
                             unsigned short* __restrict__ wrec) {
  int tid = blockIdx.x * 256 + threadIdx.x;
  if (tid < 409600) {
    int o = tid / 1600, k = tid % 1600;
    int kk = k >> 6, ci = k & 63;            // k = kk*64 + ci
    wff[tid] = f2bf(wff_f[o * 1600 + ci * 25 + kk]);
  } else if (tid < 409600 + 65536) {
    int i = tid - 409600;
    wrec[i] = f2bf(wrec_f[i]);
  }
}

// ---------------------------------------------------------------------------
// Conv as implicit GEMM, D[n][oc]. Block tile 128(n) x 128(oc), BK=32.
// Grid (900, 2). Writes u0 bf16 [oc][n] (uint2 along n) and a bf16 [n][oc].
__global__ __launch_bounds__(256) void conv_kernel(
    const float* __restrict__ x, const float* __restrict__ thr,
    const unsigned short* __restrict__ wff,
    unsigned short* __restrict__ u0_cn, unsigned short* __restrict__ a_nc) {
  __shared__ short As[128 * 40];   // x-tile  [n][k]  pad 32->40
  __shared__ short Bs[128 * 40];   // wff     [oc][k]
  const int t = threadIdx.x;
  const int n0 = blockIdx.x * 128;
  const int oc0 = blockIdx.y * 128;
  const int lane = t & 63, w = t >> 6;
  const int q = lane >> 4, r = lane & 15;
  const int wm = w >> 1, wn = w & 1;       // wm: n-half, wn: oc-half

  // x-gather per-thread spatial decode
  const int bn = t & 127;
  const int ng = n0 + bn;
  const int bb = ng / 3600;
  const int rem = ng - bb * 3600;
  const int yy = rem / 60;
  const int xx = rem - yy * 60;
  const int bybase = bb * CHW + yy * 64 + xx;
  const int boct0 = t >> 7;

  f32x4 acc[4][4];
#pragma unroll
  for (int i = 0; i < 4; i++)
#pragma unroll
    for (int j = 0; j < 4; j++) acc[i][j] = (f32x4){0.f, 0.f, 0.f, 0.f};

  for (int c = 0; c < 50; ++c) {
    const int k0 = c * 32;
    const int kk = c >> 1;                 // ky*5+kx, uniform per chunk
    const int ky = kk / 5, kx = kk - ky * 5;
    const int cibase = (c & 1) * 32;
    const int gbase = bybase + ky * 64 + kx;

    __syncthreads();
    // stage wff: 128 oc-rows x 32 k = 512 16B tasks, 2 passes
#pragma unroll
    for (int p = 0; p < 2; ++p) {
      int s = p * 256 + t;
      int m = s >> 2, qt = s & 3;
      *(int4*)(&Bs[m * 40 + qt * 8]) =
          *(const int4*)(wff + (oc0 + m) * 1600 + k0 + qt * 8);
    }
    // stage x: gather fp32, convert, write 8-bf16 groups
#pragma unroll
    for (int p = 0; p < 2; ++p) {
      int oct = boct0 + p * 2;
      int ci = cibase + oct * 8;
      alignas(16) unsigned short tmp[8];
#pragma unroll
      for (int jj = 0; jj < 8; ++jj)
        tmp[jj] = f2bf(x[gbase + (ci + jj) * HW2]);
      *(int4*)(&As[bn * 40 + oct * 8]) = *(const int4*)tmp;
    }
    __syncthreads();

    short8 xf[4], wf[4];
#pragma unroll
    for (int i = 0; i < 4; i++)
      xf[i] = *(const short8*)(&As[(wm * 64 + i * 16 + r) * 40 + q * 8]);
#pragma unroll
    for (int j = 0; j < 4; j++)
      wf[j] = *(const short8*)(&Bs[(wn * 64 + j * 16 + r) * 40 + q * 8]);
#pragma unroll
    for (int i = 0; i < 4; i++)
#pragma unroll
      for (int j = 0; j < 4; j++)
        acc[i][j] = __builtin_amdgcn_mfma_f32_16x16x32_bf16(xf[i], wf[j],
                                                            acc[i][j], 0, 0, 0);
  }

  // epilogue: rows = n (q*4+d), cols = oc (r)
#pragma unroll
  for (int i = 0; i < 4; i++) {
    const int nb = n0 + wm * 64 + i * 16 + q * 4;
#pragma unroll
    for (int j = 0; j < 4; j++) {
      const int oc = oc0 + wn * 64 + j * 16 + r;
      const float th = thr[oc];
      alignas(8) unsigned short up[4];
#pragma unroll
      for (int d = 0; d < 4; ++d) {
        float v = acc[i][j][d];
        up[d] = f2bf(v);
        float a = v - th;
        a_nc[(nb + d) * 256 + oc] = f2bf(a > 0.f ? a : 0.f);
      }
      *(uint2*)(&u0_cn[oc * NTOT + nb]) = *(const uint2*)up;
    }
  }
}

// ---------------------------------------------------------------------------
// One fixed-point iteration, D[n][oc]. Block tile 128(n) x 128(oc), grid
// (900,2). Fused: rec GEMM -> u update (float4 NCHW) -> a (bf16) -> norms.
template <int FIRST>
__global__ __launch_bounds__(256) void iter_kernel(
    const unsigned short* __restrict__ wrec,
    const unsigned short* __restrict__ u0_cn, const float* __restrict__ thr,
    float* __restrict__ u, unsigned short* __restrict__ a_nc,
    float* __restrict__ norms, int* __restrict__ flag, int it) {
  __shared__ short As[128 * 40];   // a-tile [n][k]
  __shared__ short Bs[128 * 40];   // wrec   [oc][k]
  __shared__ float red[8];

  const int t = threadIdx.x;
  if (!FIRST) {
    if (*(volatile int*)flag) return;                      // converged earlier
    float d2p = norms[2 * (it - 1)], n2p = norms[2 * (it - 1) + 1];
    if (d2p < 1e-6f * n2p) {                               // fro ratio < 1e-3
      if (t == 0) *flag = 1;
      return;
    }
  }

  const int n0 = blockIdx.x * 128;
  const int oc0 = blockIdx.y * 128;
  const int lane = t & 63, w = t >> 6;
  const int q = lane >> 4, r = lane & 15;
  const int wm = w >> 1, wn = w & 1;

  f32x4 acc[4][4];
#pragma unroll
  for (int i = 0; i < 4; i++)
#pragma unroll
    for (int j = 0; j < 4; j++) acc[i][j] = (f32x4){0.f, 0.f, 0.f, 0.f};

  for (int c = 0; c < 8; ++c) {
    const int k0 = c * 32;
    __syncthreads();
#pragma unroll
    for (int p = 0; p < 2; ++p) {          // a-tile: 128 n-rows x 32 k
      int s = p * 256 + t;
      int m = s >> 2, qt = s & 3;
      *(int4*)(&As[m * 40 + qt * 8]) =
          *(const int4*)(a_nc + (n0 + m) * 256 + k0 + qt * 8);
    }
#pragma unroll
    for (int p = 0; p < 2; ++p) {          // wrec: 128 oc-rows x 32 k
      int s = p * 256 + t;
      int m = s >> 2, qt = s & 3;
      *(int4*)(&Bs[m * 40 + qt * 8]) =
          *(const int4*)(wrec + (oc0 + m) * 256 + k0 + qt * 8);
    }
    __syncthreads();

    short8 af[4], wf[4];
#pragma unroll
    for (int i = 0; i < 4; i++)
      af[i] = *(const short8*)(&As[(wm * 64 + i * 16 + r) * 40 + q * 8]);
#pragma unroll
    for (int j = 0; j < 4; j++)
      wf[j] = *(const short8*)(&Bs[(wn * 64 + j * 16 + r) * 40 + q * 8]);
#pragma unroll
    for (int i = 0; i < 4; i++)
#pragma unroll
      for (int j = 0; j < 4; j++)
        acc[i][j] = __builtin_amdgcn_mfma_f32_16x16x32_bf16(af[i], wf[j],
                                                            acc[i][j], 0, 0, 0);
  }

  // fused update epilogue: lane has 4 consecutive n (d) at fixed oc
  float d2 = 0.f, n2 = 0.f;
#pragma unroll
  for (int i = 0; i < 4; i++) {
    const int nb = n0 + wm * 64 + i * 16 + q * 4;
    const int b = nb / 3600;
    const int s = nb - b * 3600;             // same b for d=0..3 (16 | 3600)
    const long ubase = (long)b * 921600 + s; // NCHW
#pragma unroll
    for (int j = 0; j < 4; j++) {
      const int oc = oc0 + wn * 64 + j * 16 + r;
      const float th = thr[oc];
      float* uptr = u + ubase + oc * 3600;
      float4 uold;
      if (FIRST) uold = (float4){0.f, 0.f, 0.f, 0.f};
      else       uold = *(const float4*)uptr;
      uint2 u0p = *(const uint2*)(&u0_cn[oc * NTOT + nb]);
      const unsigned short* u0s = (const unsigned short*)&u0p;
      float4 unew;
      float uo[4] = {uold.x, uold.y, uold.z, uold.w};
      float un[4];
#pragma unroll
      for (int d = 0; d < 4; ++d) {
        un[d] = 0.5f * uo[d] + 0.5f * (bf2f(u0s[d]) - acc[i][j][d]);
        float df = un[d] - uo[d];
        d2 += df * df;
        n2 += un[d] * un[d];
        float a = un[d] - th;
        a_nc[(nb + d) * 256 + oc] = f2bf(a > 0.f ? a : 0.f);
      }
      unew.x = un[0]; unew.y = un[1]; unew.z = un[2]; unew.w = un[3];
      *(float4*)uptr = unew;
    }
  }

  // block reduction -> atomicAdd into this iteration's norm slots
#pragma unroll
  for (int off = 32; off; off >>= 1) {
    d2 += __shfl_down(d2, off, 64);
    n2 += __shfl_down(n2, off, 64);
  }
  if (lane == 0) { red[w] = d2; red[4 + w] = n2; }
  __syncthreads();
  if (t == 0) {
    atomicAdd(&norms[2 * it], red[0] + red[1] + red[2] + red[3]);
    atomicAdd(&norms[2 * it + 1], red[4] + red[5] + red[6] + red[7]);
  }
}

// ---------------------------------------------------------------------------
// Final: out = relu(u - thr) in place (u already NCHW fp32 in d_out).
__global__ __launch_bounds__(256) void final_relu(float* __restrict__ out,
                                                  const float* __restrict__ thr) {
  int idx = blockIdx.x * 256 + threadIdx.x;
  int base = idx * 4;
  int c = (base / 3600) & 255;
  float th = thr[c];
  float4 v = *(float4*)(out + base);
  v.x = fmaxf(v.x - th, 0.f);
  v.y = fmaxf(v.y - th, 0.f);
  v.z = fmaxf(v.z - th, 0.f);
  v.w = fmaxf(v.w - th, 0.f);
  *(float4*)(out + base) = v;
}

// ---------------------------------------------------------------------------
extern "C" void kernel_launch(void* const* d_in, const int* in_sizes, int n_in,
                              void* d_out, int out_size, void* d_ws,
                              size_t ws_size, hipStream_t stream) {
  const float* x      = (const float*)d_in[0];
  const float* wff_f  = (const float*)d_in[1];
  const float* wrec_f = (const float*)d_in[2];
  const float* thr    = (const float*)d_in[3];
  float* u = (float*)d_out;  // u state lives in d_out (NCHW fp32)

  char* ws = (char*)d_ws;
  int* flag = (int*)ws;                                   // [0,4)
  float* norms = (float*)(ws + 64);                       // [64, 416)
  unsigned short* wff  = (unsigned short*)(ws + 1024);    // 819200 B
  unsigned short* wrec = (unsigned short*)(ws + 851968);  // 131072 B
  unsigned short* u0   = (unsigned short*)(ws + 1048576); // 58982400 B
  unsigned short* a    = (unsigned short*)(ws + 60030976);// 58982400 B
  // total ws needed: ~119 MB

  hipMemsetAsync(d_ws, 0, 1024, stream);  // flag + norm slots
  cast_weights<<<1856, 256, 0, stream>>>(wff_f, wrec_f, wff, wrec);
  conv_kernel<<<dim3(900, 2), 256, 0, stream>>>(x, thr, wff, u0, a);
  iter_kernel<1><<<dim3(900, 2), 256, 0, stream>>>(wrec, u0, thr, u, a, norms,
                                                   flag, 1);
  for (int it = 2; it <= 41; ++it)   // max_iter = 40 -> up to 41 bodies
    iter_kernel<0><<<dim3(900, 2), 256, 0, stream>>>(wrec, u0, thr, u, a,
                                                     norms, flag, it);
  final_relu<<<28800, 256, 0, stream>>>(u, thr);
}

// Round 3
// 1795.072 us; speedup vs baseline: 1.6036x; 1.0163x over previous
//
#include <hip/hip_runtime.h>

// ---------------------------------------------------------------------------
// SparsePoolingLayer: u0 = conv5x5_valid(x, W_ff); iterate
//   u <- 0.5*u + 0.5*(u0 - W_rec @ a); a = relu(u - thr)
// until ||u_new - u||/||u_new|| < 1e-3 (device-checked), max 41 iterations.
//
// R2 change: x is pre-transposed once to NHWC bf16 (transpose_x). Conv A-tile
// staging becomes contiguous int4 loads with a scalar-uniform per-chunk
// offset (VALUBusy 40% and 1.7e7 LDS bank conflicts in R1 came from the
// 800 scalar fp32 gathers + f2bf per thread and row-per-lane ds_write_b128).
// iter_kernel intentionally unchanged to isolate the conv experiment.
// ---------------------------------------------------------------------------

typedef __attribute__((ext_vector_type(8))) short short8;
typedef __attribute__((ext_vector_type(4))) float f32x4;

#define NTOT 115200   // 32*60*60
#define CHW  262144   // 64*64*64
#define HW2  4096     // 64*64

__device__ __forceinline__ unsigned short f2bf(float f) {
  unsigned int u = __float_as_uint(f);
  unsigned int r = u + 0x7FFFu + ((u >> 16) & 1u);
  return (unsigned short)(r >> 16);
}
__device__ __forceinline__ float bf2f(unsigned short h) {
  return __uint_as_float(((unsigned int)h) << 16);
}

// ---------------------------------------------------------------------------
// Weight cast/reorder: W_ff[o][ci][ky][kx] -> wff[o][(ky*5+kx)*64 + ci] bf16
//                      W_rec[o][i]         -> wrec[o*256+i] bf16
__global__ void cast_weights(const float* __restrict__ wff_f,
                             const float* __restrict__ wrec_f,
                             unsigned short* __restrict__ wff,
                             unsigned short* __restrict__ wrec) {
  int tid = blockIdx.x * 256 + threadIdx.x;
  if (tid < 409600) {
    int o = tid / 1600, k = tid % 1600;
    int kk = k >> 6, ci = k & 63;            // k = kk*64 + ci
    wff[tid] = f2bf(wff_f[o * 1600 + ci * 25 + kk]);
  } else if (tid < 409600 + 65536) {
    int i = tid - 409600;
    wrec[i] = f2bf(wrec_f[i]);
  }
}

// ---------------------------------------------------------------------------
// x NCHW fp32 -> NHWC bf16: xt[(b*4096 + y*64 + x)*64 + ci].
// Lane owns one pixel; reads coalesced across lanes (consecutive yx), writes
// int4 per 8-ci octant (L2 merges the 8 partial line writes).
__global__ __launch_bounds__(256) void transpose_x(
    const float* __restrict__ x, unsigned short* __restrict__ xt) {
  int g = blockIdx.x * 256 + threadIdx.x;          // 131072 = 32*4096
  const float* src = x + (long)(g >> 12) * CHW + (g & 4095);
  unsigned short* dst = xt + (long)g * 64;
#pragma unroll
  for (int oct = 0; oct < 8; ++oct) {
    alignas(16) unsigned short tmp[8];
#pragma unroll
    for (int d = 0; d < 8; ++d)
      tmp[d] = f2bf(src[(oct * 8 + d) * HW2]);
    *(int4*)(dst + oct * 8) = *(const int4*)tmp;
  }
}

// ---------------------------------------------------------------------------
// Conv as implicit GEMM, D[n][oc]. Block tile 128(n) x 128(oc), BK=32.
// Grid (900, 2). Writes u0 bf16 [oc][n] (uint2 along n) and a bf16 [n][oc].
__global__ __launch_bounds__(256) void conv_kernel(
    const unsigned short* __restrict__ xt, const float* __restrict__ thr,
    const unsigned short* __restrict__ wff,
    unsigned short* __restrict__ u0_cn, unsigned short* __restrict__ a_nc) {
  __shared__ short As[128 * 40];   // x-tile  [n][k]  pad 32->40
  __shared__ short Bs[128 * 40];   // wff     [oc][k]
  const int t = threadIdx.x;
  const int n0 = blockIdx.x * 128;
  const int oc0 = blockIdx.y * 128;
  const int lane = t & 63, w = t >> 6;
  const int q = lane >> 4, r = lane & 15;
  const int wm = w >> 1, wn = w & 1;       // wm: n-half, wn: oc-half
  const int qt = t & 3, mrow = t >> 2;     // staging task: row mrow(+64), 16B qt

  // per-thread x base (element index into xt) for my two staging rows
  int xbase[2];
#pragma unroll
  for (int p = 0; p < 2; ++p) {
    int n = n0 + p * 64 + mrow;
    int bb = n / 3600, rem = n - bb * 3600;
    int yy = rem / 60, xx = rem - yy * 60;
    xbase[p] = (bb * 4096 + yy * 64 + xx) * 64 + qt * 8;
  }

  f32x4 acc[4][4];
#pragma unroll
  for (int i = 0; i < 4; i++)
#pragma unroll
    for (int j = 0; j < 4; j++) acc[i][j] = (f32x4){0.f, 0.f, 0.f, 0.f};

  for (int c = 0; c < 50; ++c) {
    const int k0 = c * 32;
    const int kk = c >> 1;                 // ky*5+kx, uniform per chunk
    const int ky = kk / 5, kx = kk - ky * 5;
    const int choff = (ky * 64 + kx) * 64 + (c & 1) * 32;  // scalar-uniform

    __syncthreads();
#pragma unroll
    for (int p = 0; p < 2; ++p) {          // wff: 128 oc-rows x 32 k
      int m = p * 64 + mrow;
      *(int4*)(&Bs[m * 40 + qt * 8]) =
          *(const int4*)(wff + (oc0 + m) * 1600 + k0 + qt * 8);
    }
#pragma unroll
    for (int p = 0; p < 2; ++p) {          // x-tile: contiguous bf16 from NHWC
      int m = p * 64 + mrow;
      *(int4*)(&As[m * 40 + qt * 8]) = *(const int4*)(xt + xbase[p] + choff);
    }
    __syncthreads();

    short8 xf[4], wf[4];
#pragma unroll
    for (int i = 0; i < 4; i++)
      xf[i] = *(const short8*)(&As[(wm * 64 + i * 16 + r) * 40 + q * 8]);
#pragma unroll
    for (int j = 0; j < 4; j++)
      wf[j] = *(const short8*)(&Bs[(wn * 64 + j * 16 + r) * 40 + q * 8]);
#pragma unroll
    for (int i = 0; i < 4; i++)
#pragma unroll
      for (int j = 0; j < 4; j++)
        acc[i][j] = __builtin_amdgcn_mfma_f32_16x16x32_bf16(xf[i], wf[j],
                                                            acc[i][j], 0, 0, 0);
  }

  // epilogue: rows = n (q*4+d), cols = oc (r)
#pragma unroll
  for (int i = 0; i < 4; i++) {
    const int nb = n0 + wm * 64 + i * 16 + q * 4;
#pragma unroll
    for (int j = 0; j < 4; j++) {
      const int oc = oc0 + wn * 64 + j * 16 + r;
      const float th = thr[oc];
      alignas(8) unsigned short up[4];
#pragma unroll
      for (int d = 0; d < 4; ++d) {
        float v = acc[i][j][d];
        up[d] = f2bf(v);
        float a = v - th;
        a_nc[(nb + d) * 256 + oc] = f2bf(a > 0.f ? a : 0.f);
      }
      *(uint2*)(&u0_cn[oc * NTOT + nb]) = *(const uint2*)up;
    }
  }
}

// ---------------------------------------------------------------------------
// One fixed-point iteration, D[n][oc]. Block tile 128(n) x 128(oc), grid
// (900,2). Fused: rec GEMM -> u update (float4 NCHW) -> a (bf16) -> norms.
template <int FIRST>
__global__ __launch_bounds__(256) void iter_kernel(
    const unsigned short* __restrict__ wrec,
    const unsigned short* __restrict__ u0_cn, const float* __restrict__ thr,
    float* __restrict__ u, unsigned short* __restrict__ a_nc,
    float* __restrict__ norms, int* __restrict__ flag, int it) {
  __shared__ short As[128 * 40];   // a-tile [n][k]
  __shared__ short Bs[128 * 40];   // wrec   [oc][k]
  __shared__ float red[8];

  const int t = threadIdx.x;
  if (!FIRST) {
    if (*(volatile int*)flag) return;                      // converged earlier
    float d2p = norms[2 * (it - 1)], n2p = norms[2 * (it - 1) + 1];
    if (d2p < 1e-6f * n2p) {                               // fro ratio < 1e-3
      if (t == 0) *flag = 1;
      return;
    }
  }

  const int n0 = blockIdx.x * 128;
  const int oc0 = blockIdx.y * 128;
  const int lane = t & 63, w = t >> 6;
  const int q = lane >> 4, r = lane & 15;
  const int wm = w >> 1, wn = w & 1;

  f32x4 acc[4][4];
#pragma unroll
  for (int i = 0; i < 4; i++)
#pragma unroll
    for (int j = 0; j < 4; j++) acc[i][j] = (f32x4){0.f, 0.f, 0.f, 0.f};

  for (int c = 0; c < 8; ++c) {
    const int k0 = c * 32;
    __syncthreads();
#pragma unroll
    for (int p = 0; p < 2; ++p) {          // a-tile: 128 n-rows x 32 k
      int s = p * 256 + t;
      int m = s >> 2, qt = s & 3;
      *(int4*)(&As[m * 40 + qt * 8]) =
          *(const int4*)(a_nc + (n0 + m) * 256 + k0 + qt * 8);
    }
#pragma unroll
    for (int p = 0; p < 2; ++p) {          // wrec: 128 oc-rows x 32 k
      int s = p * 256 + t;
      int m = s >> 2, qt = s & 3;
      *(int4*)(&Bs[m * 40 + qt * 8]) =
          *(const int4*)(wrec + (oc0 + m) * 256 + k0 + qt * 8);
    }
    __syncthreads();

    short8 af[4], wf[4];
#pragma unroll
    for (int i = 0; i < 4; i++)
      af[i] = *(const short8*)(&As[(wm * 64 + i * 16 + r) * 40 + q * 8]);
#pragma unroll
    for (int j = 0; j < 4; j++)
      wf[j] = *(const short8*)(&Bs[(wn * 64 + j * 16 + r) * 40 + q * 8]);
#pragma unroll
    for (int i = 0; i < 4; i++)
#pragma unroll
      for (int j = 0; j < 4; j++)
        acc[i][j] = __builtin_amdgcn_mfma_f32_16x16x32_bf16(af[i], wf[j],
                                                            acc[i][j], 0, 0, 0);
  }

  // fused update epilogue: lane has 4 consecutive n (d) at fixed oc
  float d2 = 0.f, n2 = 0.f;
#pragma unroll
  for (int i = 0; i < 4; i++) {
    const int nb = n0 + wm * 64 + i * 16 + q * 4;
    const int b = nb / 3600;
    const int s = nb - b * 3600;             // same b for d=0..3 (16 | 3600)
    const long ubase = (long)b * 921600 + s; // NCHW
#pragma unroll
    for (int j = 0; j < 4; j++) {
      const int oc = oc0 + wn * 64 + j * 16 + r;
      const float th = thr[oc];
      float* uptr = u + ubase + oc * 3600;
      float4 uold;
      if (FIRST) uold = (float4){0.f, 0.f, 0.f, 0.f};
      else       uold = *(const float4*)uptr;
      uint2 u0p = *(const uint2*)(&u0_cn[oc * NTOT + nb]);
      const unsigned short* u0s = (const unsigned short*)&u0p;
      float4 unew;
      float uo[4] = {uold.x, uold.y, uold.z, uold.w};
      float un[4];
#pragma unroll
      for (int d = 0; d < 4; ++d) {
        un[d] = 0.5f * uo[d] + 0.5f * (bf2f(u0s[d]) - acc[i][j][d]);
        float df = un[d] - uo[d];
        d2 += df * df;
        n2 += un[d] * un[d];
        float a = un[d] - th;
        a_nc[(nb + d) * 256 + oc] = f2bf(a > 0.f ? a : 0.f);
      }
      unew.x = un[0]; unew.y = un[1]; unew.z = un[2]; unew.w = un[3];
      *(float4*)uptr = unew;
    }
  }

  // block reduction -> atomicAdd into this iteration's norm slots
#pragma unroll
  for (int off = 32; off; off >>= 1) {
    d2 += __shfl_down(d2, off, 64);
    n2 += __shfl_down(n2, off, 64);
  }
  if (lane == 0) { red[w] = d2; red[4 + w] = n2; }
  __syncthreads();
  if (t == 0) {
    atomicAdd(&norms[2 * it], red[0] + red[1] + red[2] + red[3]);
    atomicAdd(&norms[2 * it + 1], red[4] + red[5] + red[6] + red[7]);
  }
}

// ---------------------------------------------------------------------------
// Final: out = relu(u - thr) in place (u already NCHW fp32 in d_out).
__global__ __launch_bounds__(256) void final_relu(float* __restrict__ out,
                                                  const float* __restrict__ thr) {
  int idx = blockIdx.x * 256 + threadIdx.x;
  int base = idx * 4;
  int c = (base / 3600) & 255;
  float th = thr[c];
  float4 v = *(float4*)(out + base);
  v.x = fmaxf(v.x - th, 0.f);
  v.y = fmaxf(v.y - th, 0.f);
  v.z = fmaxf(v.z - th, 0.f);
  v.w = fmaxf(v.w - th, 0.f);
  *(float4*)(out + base) = v;
}

// ---------------------------------------------------------------------------
extern "C" void kernel_launch(void* const* d_in, const int* in_sizes, int n_in,
                              void* d_out, int out_size, void* d_ws,
                              size_t ws_size, hipStream_t stream) {
  const float* x      = (const float*)d_in[0];
  const float* wff_f  = (const float*)d_in[1];
  const float* wrec_f = (const float*)d_in[2];
  const float* thr    = (const float*)d_in[3];
  float* u = (float*)d_out;  // u state lives in d_out (NCHW fp32)

  char* ws = (char*)d_ws;
  int* flag = (int*)ws;                                    // [0,4)
  float* norms = (float*)(ws + 64);                        // [64, 416)
  unsigned short* wff  = (unsigned short*)(ws + 1024);     // 819200 B
  unsigned short* wrec = (unsigned short*)(ws + 851968);   // 131072 B
  unsigned short* xt   = (unsigned short*)(ws + 983040);   // 16777216 B
  unsigned short* u0   = (unsigned short*)(ws + 17760256); // 58982400 B
  unsigned short* a    = (unsigned short*)(ws + 76742656); // 58982400 B
  // total ws needed: ~136 MB

  hipMemsetAsync(d_ws, 0, 1024, stream);  // flag + norm slots
  cast_weights<<<1856, 256, 0, stream>>>(wff_f, wrec_f, wff, wrec);
  transpose_x<<<512, 256, 0, stream>>>(x, xt);
  conv_kernel<<<dim3(900, 2), 256, 0, stream>>>(xt, thr, wff, u0, a);
  iter_kernel<1><<<dim3(900, 2), 256, 0, stream>>>(wrec, u0, thr, u, a, norms,
                                                   flag, 1);
  for (int it = 2; it <= 41; ++it)   // max_iter = 40 -> up to 41 bodies
    iter_kernel<0><<<dim3(900, 2), 256, 0, stream>>>(wrec, u0, thr, u, a,
                                                     norms, flag, it);
  final_relu<<<28800, 256, 0, stream>>>(u, thr);
}